// Round 9
// baseline (43.186 us; speedup 1.0000x reference)
//
#include <hip/hip_runtime.h>

#define OH 532
#define OW 532
#define PWID 536
#define HW (PWID*PWID)
#define NREC 75
#define NPIX (OH*OW)

typedef _Float16 half_t;

// direct global->LDS DMA, 16 B per lane, linear wave layout
__device__ __forceinline__ void gload_lds16(const float4* g, float4* l) {
    __builtin_amdgcn_global_load_lds(
        (const __attribute__((address_space(1))) void*)g,
        (__attribute__((address_space(3))) void*)l,
        16, 0, 0);
}

// ---------------- stage 1: TXW=108, 512 threads, 4 blocks/CU ----------------
#define TXW 108
#define SREC (TXW+8)                      // 116
#define NCHUNK 5                          // 5*108 = 540 >= 536
#define NB_F (NCHUNK*PWID*2)              // 5360 fold blocks
#define NB_M 96                           // 6 ch x 16 subs (at grid FRONT)
#define S1_LDS ((SREC*NREC + SREC)*4)     // 35264 B -> 4 blocks/CU

__global__ __launch_bounds__(512) void fold_s1(const float* __restrict__ deno,
                                               const float* __restrict__ pw,
                                               const float* __restrict__ noisy,
                                               float* __restrict__ part,
                                               half_t* __restrict__ colacc) {
    extern __shared__ float smem[];
    const int bid = blockIdx.x;
    const int tid = threadIdx.x;

    if (bid < NB_M) {
        // ---- means partial block: part[ch*16+sub] = partial raw sum of noisy ----
        const int k  = bid;              // 0..95
        const int ch = k >> 4;           // 0..5
        const int sub = k & 15;
        const float4* src = (const float4*)(noisy + (size_t)ch * NPIX);
        const int n4 = NPIX / 4;         // 70756
        const int chunk = (n4 + 15) / 16;
        const int beg = sub * chunk;
        const int end = min(beg + chunk, n4);
        float s = 0.f;
        for (int i = beg + tid; i < end; i += 512) {
            float4 v = src[i];
            s += v.x + v.y + v.z + v.w;
        }
        smem[tid] = s;
        __syncthreads();
        for (int off = 256; off > 0; off >>= 1) {
            if (tid < off) smem[tid] += smem[tid + off];
            __syncthreads();
        }
        if (tid == 0) part[k] = smem[0];
        return;
    }

    float* lds  = smem;                // [SREC*NREC]
    float* ldsw = smem + SREC * NREC;  // [SREC]

    const int id = bid - NB_M;
    const int bx = id % NCHUNK;
    const int py = (id / NCHUNK) % PWID;
    const int t  = id / (NCHUNK * PWID);
    const int x0 = bx * TXW;
    const int b0 = x0 - 4;
    const int lo = b0 < 0 ? 0 : b0;                  // multiple of 4
    int hi = x0 + TXW + 4; if (hi > PWID) hi = PWID; // multiple of 4

    // stage weights first so their latency hides under the record stream
    const float* wsrc = pw + (size_t)t * HW + (size_t)py * PWID;
    for (int k = lo + tid; k < hi; k += 512) ldsw[k - b0] = wsrc[k];

    // stage records [lo, hi): contiguous, 16B-aligned, length %4 == 0
    const float* src = deno + ((size_t)t * HW + (size_t)py * PWID + lo) * NREC;
    const float4* s4 = (const float4*)src;
    float4* d4 = (float4*)(lds + (lo - b0) * NREC);
    const int n4 = ((hi - lo) * NREC) >> 2;

    const int wave = tid >> 6;
    const int lane = tid & 63;
    const int nchunk = n4 >> 6;          // full 64-float4 wave chunks
    for (int c = wave; c < nchunk; c += 8) {
        const int base = (c << 6) + lane;
        gload_lds16(s4 + base, d4 + base);
    }
    for (int k = (nchunk << 6) + tid; k < n4; k += 512) d4[k] = s4[k];
    __syncthreads();

    const int lx = tid & 127;         // group of 128 covers 108 X
    const int grp = tid >> 7;         // 0..3, each handles 4 planes
    const int X = x0 + lx;
    if (lx >= TXW || X >= PWID) return;

    half_t* cbase = colacc + (size_t)t * 16 * HW + (size_t)py * PWID + X;
#pragma unroll
    for (int k = 0; k < 4; ++k) {
        const int ci = grp * 4 + k;
        float acc = 0.f;
        if (ci < 15) {
            const int c = ci / 5, i = ci % 5;
#pragma unroll
            for (int j = 0; j < 5; ++j) {
                const int lpx = lx + 4 - j;
                acc += lds[lpx * NREC + c * 25 + i * 5 + j] * ldsw[lpx];
            }
        } else {
#pragma unroll
            for (int j = 0; j < 5; ++j) acc += ldsw[lx + 4 - j];
        }
        cbase[(size_t)ci * HW] = (half_t)acc;
    }
}

// ---------------- stage 2: vertical fold + finalize (4 px/thread) ----------------
struct alignas(8) h4 { half_t a, b, c, d; };

__global__ __launch_bounds__(256) void fold_s2(const half_t* __restrict__ colacc,
                                               const float* __restrict__ part,
                                               float* __restrict__ out) {
    const int t = blockIdx.y;
    __shared__ float m3[3];
    if (threadIdx.x < 3) {
        const float* p = part + t * 48 + threadIdx.x * 16;
        float s = 0.f;
#pragma unroll
        for (int i = 0; i < 16; ++i) s += p[i];
        m3[threadIdx.x] = s * (1.f / (float)NPIX);   // == mean*0.5+0.5
    }
    __syncthreads();

    const int NQ = OW / 4;   // 133
    int id = blockIdx.x * 256 + threadIdx.x;
    if (id >= OH * NQ) return;
    int xq = id % NQ;
    int y  = id / NQ;
    int x = xq * 4;

    const half_t* ca = colacc + (size_t)t * 16 * HW + (size_t)(y + 4) * PWID + (x + 4);

    float w0 = 0.f, w1 = 0.f, w2 = 0.f, w3 = 0.f;
#pragma unroll
    for (int i = 0; i < 5; ++i) {
        h4 v = *(const h4*)(ca + (size_t)15 * HW - (size_t)i * PWID);
        w0 += (float)v.a; w1 += (float)v.b; w2 += (float)v.c; w3 += (float)v.d;
    }
    const float i0 = 0.5f / w0, i1 = 0.5f / w1, i2 = 0.5f / w2, i3 = 0.5f / w3;

    const size_t ob = ((size_t)t * 3 * OH + y) * OW + x;
#pragma unroll
    for (int c = 0; c < 3; ++c) {
        float s0 = 0.f, s1 = 0.f, s2 = 0.f, s3 = 0.f;
#pragma unroll
        for (int i = 0; i < 5; ++i) {
            h4 v = *(const h4*)(ca + (size_t)(c * 5 + i) * HW - (size_t)i * PWID);
            s0 += (float)v.a; s1 += (float)v.b; s2 += (float)v.c; s3 += (float)v.d;
        }
        const float m = m3[c];
        float4 o;
        o.x = s0 * i0 + m; o.y = s1 * i1 + m; o.z = s2 * i2 + m; o.w = s3 * i3 + m;
        *(float4*)(out + ob + (size_t)c * OH * OW) = o;
    }
}

// ---------------- fallback path (ws too small): proven 3-kernel route ----------------
__global__ __launch_bounds__(256) void means_part_fb(const float* __restrict__ noisy,
                                                     float* __restrict__ part) {
    const int k  = blockIdx.x;
    const int ch = k >> 6;
    const int b  = k & 63;
    const float4* src = (const float4*)(noisy + (size_t)ch * NPIX);
    const int n4 = NPIX / 4;
    const int chunk = (n4 + 63) / 64;
    const int beg = b * chunk;
    const int end = min(beg + chunk, n4);
    float s = 0.f;
    for (int i = beg + threadIdx.x; i < end; i += 256) {
        float4 v = src[i];
        s += v.x + v.y + v.z + v.w;
    }
    __shared__ float red[256];
    red[threadIdx.x] = s;
    __syncthreads();
    for (int off = 128; off > 0; off >>= 1) {
        if (threadIdx.x < off) red[threadIdx.x] += red[threadIdx.x + off];
        __syncthreads();
    }
    if (threadIdx.x == 0) part[k] = red[0];
}

__global__ void means_final_fb(const float* __restrict__ part, float* __restrict__ msum) {
    int w = threadIdx.x >> 6;
    int lane = threadIdx.x & 63;
    float s = part[w * 64 + lane];
    for (int off = 32; off > 0; off >>= 1) s += __shfl_down(s, off, 64);
    if (lane == 0) msum[w] = s;
}

#define TW 16
#define TH 16
#define FR (TH+4)
#define FC (TW+4)
#define ROWF (FC*NREC)
#define SMEM_BYTES ((FR*ROWF + FR*FC)*4)

__global__ void fold_tile(const float* __restrict__ deno,
                          const float* __restrict__ pw,
                          const float* __restrict__ msum,
                          float* __restrict__ out) {
    extern __shared__ float smem[];
    float* lds  = smem;
    float* ldsw = smem + FR * ROWF;

    const int t  = blockIdx.z;
    const int x0 = blockIdx.x * TW;
    const int y0 = blockIdx.y * TH;
    const int tid = threadIdx.x;
    const int rows = min(FR, PWID - y0);
    const int cols = min(FC, PWID - x0);

    const float* dbase = deno + (size_t)t * HW * NREC;
    const float* wbase = pw   + (size_t)t * HW;

    const int rowFloats = cols * NREC;
    const int row4 = rowFloats >> 2;
    const int tail = rowFloats & 3;
    for (int r = 0; r < rows; ++r) {
        const float* src = dbase + ((size_t)(y0 + r) * PWID + x0) * NREC;
        const float4* s4 = (const float4*)src;
        float4* d4 = (float4*)(lds + r * ROWF);
        for (int k = tid; k < row4; k += 256) d4[k] = s4[k];
        if (tid < tail) lds[r * ROWF + row4 * 4 + tid] = src[row4 * 4 + tid];
    }
    for (int k = tid; k < rows * cols; k += 256) {
        int pr = k / cols, pc = k - pr * cols;
        ldsw[pr * FC + pc] = wbase[(size_t)(y0 + pr) * PWID + x0 + pc];
    }
    __syncthreads();

    const int tx = tid & (TW - 1);
    const int ty = tid >> 4;
    const int x = x0 + tx;
    const int y = y0 + ty;
    if (x >= OW || y >= OH) return;

    float a0 = 0.f, a1 = 0.f, a2 = 0.f, wsv = 0.f;
#pragma unroll
    for (int pr = 0; pr < 5; ++pr) {
#pragma unroll
        for (int pc = 0; pc < 5; ++pc) {
            const int rr = ty + pr;
            const int cc = tx + pc;
            const float w = ldsw[rr * FC + cc];
            const float* rec = &lds[rr * ROWF + cc * NREC + (4 - pr) * 5 + (4 - pc)];
            a0 += rec[0]  * w;
            a1 += rec[25] * w;
            a2 += rec[50] * w;
            wsv += w;
        }
    }
    const float inv = 0.5f / wsv;
    const size_t obase = ((size_t)(t * 3) * OH + y) * OW + x;
    out[obase]                   = a0 * inv + msum[t*3+0] * (1.f/(float)NPIX);
    out[obase + (size_t)OH * OW] = a1 * inv + msum[t*3+1] * (1.f/(float)NPIX);
    out[obase + 2*(size_t)OH*OW] = a2 * inv + msum[t*3+2] * (1.f/(float)NPIX);
}

extern "C" void kernel_launch(void* const* d_in, const int* in_sizes, int n_in,
                              void* d_out, int out_size, void* d_ws, size_t ws_size,
                              hipStream_t stream) {
    const float* noisy = (const float*)d_in[0];
    const float* deno  = (const float*)d_in[1];
    const float* pw    = (const float*)d_in[2];
    float* out = (float*)d_out;

    float* part = (float*)d_ws;                       // 96 (main) / 384+6 (fallback) floats
    half_t* colacc = (half_t*)((char*)d_ws + 2048);   // 16 planes x HW x 2t, fp16

    const size_t req = 2048 + (size_t)16 * HW * 2 * sizeof(half_t);

    if (ws_size >= req) {
        hipFuncSetAttribute(reinterpret_cast<const void*>(&fold_s1),
                            hipFuncAttributeMaxDynamicSharedMemorySize, S1_LDS);
        fold_s1<<<NB_M + NB_F, 512, S1_LDS, stream>>>(deno, pw, noisy, part, colacc);
        const int NQ = OW / 4;
        dim3 g2((OH * NQ + 255) / 256, 2);
        fold_s2<<<g2, 256, 0, stream>>>(colacc, part, out);
    } else {
        float* msum = (float*)d_ws + 448;
        means_part_fb<<<384, 256, 0, stream>>>(noisy, part);
        means_final_fb<<<1, 384, 0, stream>>>(part, msum);
        hipFuncSetAttribute(reinterpret_cast<const void*>(&fold_tile),
                            hipFuncAttributeMaxDynamicSharedMemorySize, SMEM_BYTES);
        dim3 grid((OW + TW - 1) / TW, (OH + TH - 1) / TH, 2);
        fold_tile<<<grid, 256, SMEM_BYTES, stream>>>(deno, pw, msum, out);
    }
}

// Round 10
// 41.801 us; speedup vs baseline: 1.0331x; 1.0331x over previous
//
#include <hip/hip_runtime.h>

#define OH 532
#define OW 532
#define PWID 536
#define HW (PWID*PWID)
#define NREC 75
#define NPIX (OH*OW)

typedef _Float16 half_t;

// direct global->LDS DMA, 16 B per lane, linear wave layout
__device__ __forceinline__ void gload_lds16(const float4* g, float4* l) {
    __builtin_amdgcn_global_load_lds(
        (const __attribute__((address_space(1))) void*)g,
        (__attribute__((address_space(3))) void*)l,
        16, 0, 0);
}

// ---------------- stage 1: TXW=256, 512 threads, fused means partials (R8 config) ----------------
#define TXW 256
#define SREC (TXW+8)                      // 264
#define NCHUNK 3                          // ceil(536/256)
#define NB_F (NCHUNK*PWID*2)              // 3216 fold blocks
#define NB_M 96                           // 6 ch x 16 subs (at tail)
#define S1_LDS ((SREC*NREC + SREC)*4)     // 80256 B -> 2 blocks/CU

__global__ __launch_bounds__(512) void fold_s1(const float* __restrict__ deno,
                                               const float* __restrict__ pw,
                                               const float* __restrict__ noisy,
                                               float* __restrict__ part,
                                               half_t* __restrict__ colacc) {
    extern __shared__ float smem[];
    const int bid = blockIdx.x;
    const int tid = threadIdx.x;

    if (bid >= NB_F) {
        // ---- means partial block: part[ch*16+sub] = partial raw sum of noisy ----
        const int k  = bid - NB_F;       // 0..95
        const int ch = k >> 4;           // 0..5
        const int sub = k & 15;
        const float4* src = (const float4*)(noisy + (size_t)ch * NPIX);
        const int n4 = NPIX / 4;         // 70756
        const int chunk = (n4 + 15) / 16;
        const int beg = sub * chunk;
        const int end = min(beg + chunk, n4);
        float s = 0.f;
        for (int i = beg + tid; i < end; i += 512) {
            float4 v = src[i];
            s += v.x + v.y + v.z + v.w;
        }
        smem[tid] = s;
        __syncthreads();
        for (int off = 256; off > 0; off >>= 1) {
            if (tid < off) smem[tid] += smem[tid + off];
            __syncthreads();
        }
        if (tid == 0) part[k] = smem[0];
        return;
    }

    float* lds  = smem;                // [SREC*NREC]
    float* ldsw = smem + SREC * NREC;  // [SREC]

    const int bx = bid % NCHUNK;
    const int py = (bid / NCHUNK) % PWID;
    const int t  = bid / (NCHUNK * PWID);
    const int x0 = bx * TXW;
    const int b0 = x0 - 4;
    const int lo = b0 < 0 ? 0 : b0;                  // multiple of 4
    int hi = x0 + TXW + 4; if (hi > PWID) hi = PWID; // multiple of 4

    // stage weights first so their latency hides under the record stream
    const float* wsrc = pw + (size_t)t * HW + (size_t)py * PWID;
    for (int k = lo + tid; k < hi; k += 512) ldsw[k - b0] = wsrc[k];

    // stage records [lo, hi): contiguous, 16B-aligned, length %4 == 0
    const float* src = deno + ((size_t)t * HW + (size_t)py * PWID + lo) * NREC;
    const float4* s4 = (const float4*)src;
    float4* d4 = (float4*)(lds + (lo - b0) * NREC);
    const int n4 = ((hi - lo) * NREC) >> 2;

    const int wave = tid >> 6;
    const int lane = tid & 63;
    const int nchunk = n4 >> 6;          // full 64-float4 wave chunks
    for (int c = wave; c < nchunk; c += 8) {
        const int base = (c << 6) + lane;
        gload_lds16(s4 + base, d4 + base);
    }
    for (int k = (nchunk << 6) + tid; k < n4; k += 512) d4[k] = s4[k];
    __syncthreads();

    const int lx = tid & 255;
    const int half = tid >> 8;        // wave-uniform
    const int X = x0 + lx;
    if (X >= PWID) return;

    half_t* cbase = colacc + (size_t)t * 16 * HW + (size_t)py * PWID + X;
#pragma unroll
    for (int k = 0; k < 8; ++k) {
        const int ci = half * 8 + k;
        float acc = 0.f;
        if (ci < 15) {
            const int c = ci / 5, i = ci % 5;
#pragma unroll
            for (int j = 0; j < 5; ++j) {
                const int lpx = lx + 4 - j;
                acc += lds[lpx * NREC + c * 25 + i * 5 + j] * ldsw[lpx];
            }
        } else {
#pragma unroll
            for (int j = 0; j < 5; ++j) acc += ldsw[lx + 4 - j];
        }
        cbase[(size_t)ci * HW] = (half_t)acc;
    }
}

// ---------------- stage 2: vertical fold, 4 px x 2 rows per thread ----------------
struct alignas(8) h4 { half_t a, b, c, d; };

__global__ __launch_bounds__(256) void fold_s2(const half_t* __restrict__ colacc,
                                               const float* __restrict__ part,
                                               float* __restrict__ out) {
    const int t = blockIdx.y;
    __shared__ float m3[3];
    if (threadIdx.x < 3) {
        const float* p = part + t * 48 + threadIdx.x * 16;
        float s = 0.f;
#pragma unroll
        for (int i = 0; i < 16; ++i) s += p[i];
        m3[threadIdx.x] = s * (1.f / (float)NPIX);   // == mean*0.5+0.5
    }
    __syncthreads();

    const int NQ = OW / 4;    // 133
    const int NYP = OH / 2;   // 266
    int id = blockIdx.x * 256 + threadIdx.x;
    if (id >= NQ * NYP) return;
    int xq = id % NQ;
    int yp = id / NQ;
    int y0 = yp * 2;
    int x = xq * 4;

    // base at colacc row y0, col x+4; output row y0 taps rows y0+(4-i), y1 taps y0+(5-i)
    const half_t* ca = colacc + (size_t)t * 16 * HW + (size_t)y0 * PWID + (x + 4);

    // wsum plane: rows y0..y0+5
    const half_t* cw = ca + (size_t)15 * HW;
    float wa0 = 0.f, wa1 = 0.f, wa2 = 0.f, wa3 = 0.f;
    float wb0 = 0.f, wb1 = 0.f, wb2 = 0.f, wb3 = 0.f;
#pragma unroll
    for (int r = 0; r < 6; ++r) {
        h4 v = *(const h4*)(cw + (size_t)r * PWID);
        if (r < 5)  { wa0 += (float)v.a; wa1 += (float)v.b; wa2 += (float)v.c; wa3 += (float)v.d; }
        if (r >= 1) { wb0 += (float)v.a; wb1 += (float)v.b; wb2 += (float)v.c; wb3 += (float)v.d; }
    }
    const float ia0 = 0.5f / wa0, ia1 = 0.5f / wa1, ia2 = 0.5f / wa2, ia3 = 0.5f / wa3;
    const float ib0 = 0.5f / wb0, ib1 = 0.5f / wb1, ib2 = 0.5f / wb2, ib3 = 0.5f / wb3;

    const size_t obA = ((size_t)t * 3 * OH + y0) * OW + x;
#pragma unroll
    for (int c = 0; c < 3; ++c) {
        float sa0 = 0.f, sa1 = 0.f, sa2 = 0.f, sa3 = 0.f;
        float sb0 = 0.f, sb1 = 0.f, sb2 = 0.f, sb3 = 0.f;
#pragma unroll
        for (int i = 0; i < 5; ++i) {
            const half_t* cp = ca + (size_t)(c * 5 + i) * HW;
            h4 v0 = *(const h4*)(cp + (size_t)(4 - i) * PWID);
            h4 v1 = *(const h4*)(cp + (size_t)(5 - i) * PWID);
            sa0 += (float)v0.a; sa1 += (float)v0.b; sa2 += (float)v0.c; sa3 += (float)v0.d;
            sb0 += (float)v1.a; sb1 += (float)v1.b; sb2 += (float)v1.c; sb3 += (float)v1.d;
        }
        const float m = m3[c];
        float4 oA, oB;
        oA.x = sa0 * ia0 + m; oA.y = sa1 * ia1 + m; oA.z = sa2 * ia2 + m; oA.w = sa3 * ia3 + m;
        oB.x = sb0 * ib0 + m; oB.y = sb1 * ib1 + m; oB.z = sb2 * ib2 + m; oB.w = sb3 * ib3 + m;
        *(float4*)(out + obA + (size_t)c * OH * OW) = oA;
        *(float4*)(out + obA + (size_t)c * OH * OW + OW) = oB;
    }
}

// ---------------- fallback path (ws too small): proven 3-kernel route ----------------
__global__ __launch_bounds__(256) void means_part_fb(const float* __restrict__ noisy,
                                                     float* __restrict__ part) {
    const int k  = blockIdx.x;
    const int ch = k >> 6;
    const int b  = k & 63;
    const float4* src = (const float4*)(noisy + (size_t)ch * NPIX);
    const int n4 = NPIX / 4;
    const int chunk = (n4 + 63) / 64;
    const int beg = b * chunk;
    const int end = min(beg + chunk, n4);
    float s = 0.f;
    for (int i = beg + threadIdx.x; i < end; i += 256) {
        float4 v = src[i];
        s += v.x + v.y + v.z + v.w;
    }
    __shared__ float red[256];
    red[threadIdx.x] = s;
    __syncthreads();
    for (int off = 128; off > 0; off >>= 1) {
        if (threadIdx.x < off) red[threadIdx.x] += red[threadIdx.x + off];
        __syncthreads();
    }
    if (threadIdx.x == 0) part[k] = red[0];
}

__global__ void means_final_fb(const float* __restrict__ part, float* __restrict__ msum) {
    int w = threadIdx.x >> 6;
    int lane = threadIdx.x & 63;
    float s = part[w * 64 + lane];
    for (int off = 32; off > 0; off >>= 1) s += __shfl_down(s, off, 64);
    if (lane == 0) msum[w] = s;
}

#define TW 16
#define TH 16
#define FR (TH+4)
#define FC (TW+4)
#define ROWF (FC*NREC)
#define SMEM_BYTES ((FR*ROWF + FR*FC)*4)

__global__ void fold_tile(const float* __restrict__ deno,
                          const float* __restrict__ pw,
                          const float* __restrict__ msum,
                          float* __restrict__ out) {
    extern __shared__ float smem[];
    float* lds  = smem;
    float* ldsw = smem + FR * ROWF;

    const int t  = blockIdx.z;
    const int x0 = blockIdx.x * TW;
    const int y0 = blockIdx.y * TH;
    const int tid = threadIdx.x;
    const int rows = min(FR, PWID - y0);
    const int cols = min(FC, PWID - x0);

    const float* dbase = deno + (size_t)t * HW * NREC;
    const float* wbase = pw   + (size_t)t * HW;

    const int rowFloats = cols * NREC;
    const int row4 = rowFloats >> 2;
    const int tail = rowFloats & 3;
    for (int r = 0; r < rows; ++r) {
        const float* src = dbase + ((size_t)(y0 + r) * PWID + x0) * NREC;
        const float4* s4 = (const float4*)src;
        float4* d4 = (float4*)(lds + r * ROWF);
        for (int k = tid; k < row4; k += 256) d4[k] = s4[k];
        if (tid < tail) lds[r * ROWF + row4 * 4 + tid] = src[row4 * 4 + tid];
    }
    for (int k = tid; k < rows * cols; k += 256) {
        int pr = k / cols, pc = k - pr * cols;
        ldsw[pr * FC + pc] = wbase[(size_t)(y0 + pr) * PWID + x0 + pc];
    }
    __syncthreads();

    const int tx = tid & (TW - 1);
    const int ty = tid >> 4;
    const int x = x0 + tx;
    const int y = y0 + ty;
    if (x >= OW || y >= OH) return;

    float a0 = 0.f, a1 = 0.f, a2 = 0.f, wsv = 0.f;
#pragma unroll
    for (int pr = 0; pr < 5; ++pr) {
#pragma unroll
        for (int pc = 0; pc < 5; ++pc) {
            const int rr = ty + pr;
            const int cc = tx + pc;
            const float w = ldsw[rr * FC + cc];
            const float* rec = &lds[rr * ROWF + cc * NREC + (4 - pr) * 5 + (4 - pc)];
            a0 += rec[0]  * w;
            a1 += rec[25] * w;
            a2 += rec[50] * w;
            wsv += w;
        }
    }
    const float inv = 0.5f / wsv;
    const size_t obase = ((size_t)(t * 3) * OH + y) * OW + x;
    out[obase]                   = a0 * inv + msum[t*3+0] * (1.f/(float)NPIX);
    out[obase + (size_t)OH * OW] = a1 * inv + msum[t*3+1] * (1.f/(float)NPIX);
    out[obase + 2*(size_t)OH*OW] = a2 * inv + msum[t*3+2] * (1.f/(float)NPIX);
}

extern "C" void kernel_launch(void* const* d_in, const int* in_sizes, int n_in,
                              void* d_out, int out_size, void* d_ws, size_t ws_size,
                              hipStream_t stream) {
    const float* noisy = (const float*)d_in[0];
    const float* deno  = (const float*)d_in[1];
    const float* pw    = (const float*)d_in[2];
    float* out = (float*)d_out;

    float* part = (float*)d_ws;                       // 96 (main) / 384+6 (fallback) floats
    half_t* colacc = (half_t*)((char*)d_ws + 2048);   // 16 planes x HW x 2t, fp16

    const size_t req = 2048 + (size_t)16 * HW * 2 * sizeof(half_t);

    if (ws_size >= req) {
        hipFuncSetAttribute(reinterpret_cast<const void*>(&fold_s1),
                            hipFuncAttributeMaxDynamicSharedMemorySize, S1_LDS);
        fold_s1<<<NB_F + NB_M, 512, S1_LDS, stream>>>(deno, pw, noisy, part, colacc);
        const int NQ = OW / 4;
        const int NYP = OH / 2;
        dim3 g2((NQ * NYP + 255) / 256, 2);
        fold_s2<<<g2, 256, 0, stream>>>(colacc, part, out);
    } else {
        float* msum = (float*)d_ws + 448;
        means_part_fb<<<384, 256, 0, stream>>>(noisy, part);
        means_final_fb<<<1, 384, 0, stream>>>(part, msum);
        hipFuncSetAttribute(reinterpret_cast<const void*>(&fold_tile),
                            hipFuncAttributeMaxDynamicSharedMemorySize, SMEM_BYTES);
        dim3 grid((OW + TW - 1) / TW, (OH + TH - 1) / TH, 2);
        fold_tile<<<grid, 256, SMEM_BYTES, stream>>>(deno, pw, msum, out);
    }
}